// Round 11
// baseline (260.903 us; speedup 1.0000x reference)
//
#include <hip/hip_runtime.h>
#include <stdint.h>

#define HW 16384
#define NI 64
#define NM 256
#define WORDS 256

// ws layout (~3 MB used)
#define OFF_STATE  0u            // 1 MB state bytes (iter 0)
#define OFF_STATE2 (1u << 20)    // 1 MB state bytes (iter 5 handoff)
#define OFF_PACKED (2u << 20)    // 512 KB bit-packed masks [word][mask]
#define OFF_DIOUT  0x280000u     // 256 KB diou transposed diouT[col][row]
#define OFF_COMPM  0x2C0000u
#define OFF_CNT    0x2C1000u     // 64 counters + done ticket at [64]

// ---------------- setup: state init + mask pack + counter zero (proven) -----
__global__ __launch_bounds__(256) void setup_kernel(
    const float* __restrict__ seg, const float* __restrict__ x,
    const float* __restrict__ targets, unsigned char* __restrict__ state,
    unsigned long long* __restrict__ packed, int* __restrict__ counters) {
    #pragma clang fp contract(off)
    const int gid = blockIdx.x * 256 + threadIdx.x;
    for (int u = gid; u < 262144; u += 131072) {
        const int px0 = u * 4;
        const float4 xv = *(const float4*)(x + px0);
        const float4 tv = *(const float4*)(targets + px0);
        float xs[4] = {xv.x, xv.y, xv.z, xv.w};
        float ts[4] = {tv.x, tv.y, tv.z, tv.w};
        uint32_t st = 0;
        for (int j = 0; j < 4; ++j) {
            float xt = xs[j] * ts[j];
            int b1 = (xt > 0.5f) ? 1 : 0;
            int tb = (ts[j] > 0.5f) ? 1 : 0;
            st |= (uint32_t)(b1 | ((b1 ^ 1) << 1) | (tb << 2)) << (8 * j);
        }
        *(uint32_t*)(state + px0) = st;
    }
    const int wv = gid >> 6, lane = gid & 63;
    for (int t = 0; t < 32; ++t) {
        int gwi = wv * 32 + t;
        int i = gwi >> 8, w = gwi & 255;
        float v = seg[(size_t)i * HW + w * 64 + lane];
        unsigned long long m = __ballot(v > 0.5f);
        if (lane == 0) packed[w * NM + i] = m;
    }
    if (gid < NI + 1) counters[gid] = 0;
}

// ---------------- fused diou + compm (proven) -------------------------------
__global__ __launch_bounds__(256) void diou_compm_kernel(
    const unsigned long long* __restrict__ packed, const int* __restrict__ labels,
    float* __restrict__ diouT, float* __restrict__ compm) {
    #pragma clang fp contract(off)
    __shared__ unsigned long long colj[WORDS];
    __shared__ float red[NM];
    const int j = blockIdx.x, i = threadIdx.x;
    colj[i] = packed[i * NM + j];
    __syncthreads();
    int inter = 0, si = 0, sj = 0;
    for (int w = 0; w < WORDS; ++w) {
        unsigned long long a = colj[w];
        unsigned long long b = packed[w * NM + i];
        inter += __popcll(a & b);
        sj += __popcll(a);
        si += __popcll(b);
    }
    float d = 0.0f;
    if (j > i && labels[i] == labels[j]) {
        float u = (float)(si + sj - inter);
        d = (float)inter / u;
    }
    diouT[j * NM + i] = d;
    red[i] = d;
    __syncthreads();
    for (int off = 128; off > 0; off >>= 1) {
        if (i < off) red[i] = fmaxf(red[i], red[i + off]);
        __syncthreads();
    }
    if (i == 0) {
        float m = red[0];
        float t = m * m;
        compm[j] = expf(-2.0f * t);
    }
}

// ---------------- CRF: 5 iters/launch, kw PINNED in VGPRs -------------------
// 1024 blocks = 64 img x 16 tiles of 8 rows; 576 threads = 18-row window x 32
// quads. fm = feat+10 staged to LDS; each thread computes its 36 kw values
// once, then an empty asm "+v" pin makes them opaque — the allocator cannot
// rematerialize them (the R9/R10 failure mode, VGPR stuck at 40). Exact
// reference formula; OOB taps kw=0 exactly; halo argument proven bit-exact.
template <bool FIRST>
__global__ __launch_bounds__(576, 4) void crf5_kernel(
    const float* __restrict__ feat, const float* __restrict__ scores,
    const float* __restrict__ diouT, const float* __restrict__ compm,
    const unsigned char* __restrict__ gsrc, unsigned char* __restrict__ gdst2,
    float* __restrict__ out, int* __restrict__ counters) {
    #pragma clang fp contract(off)
    __shared__ float fmL[3][18 * 128];    // 27648 B
    __shared__ uint32_t stw[2][18 * 32];  // 4608 B  (total 32256 B)
    const int tid = threadIdx.x, bid = blockIdx.x;
    const int img = bid >> 4, r0 = (bid & 15) * 8;
    const int w0 = r0 - 5;
    const int rel = tid >> 5;             // 0..17
    const int xc = (tid & 31) * 4;
    const int y = w0 + rel;

    // ---- coef (phase A, blocks 0..255) — fmL as scratch --------------------
    if (FIRST && bid < NM) {
        float* red = &fmL[0][0];
        if (tid < NM) {
            float d = diouT[bid * NM + tid];
            float dd = d * d;
            float dec = expf(-2.0f * dd);
            red[tid] = dec / compm[tid];
        }
        __syncthreads();
        for (int off = 128; off > 0; off >>= 1) {
            if (tid < off) red[tid] = fminf(red[tid], red[tid + off]);
            __syncthreads();
        }
        if (tid == 0) out[bid] = scores[bid] * red[0];
        __syncthreads();
    }

    // ---- stage fm = feat + 10 (coalesced) + window state -------------------
    if ((unsigned)y < 128u) {
        const float* fb = feat + (size_t)img * 3 * HW + y * 128 + xc;
        #pragma unroll
        for (int ch = 0; ch < 3; ++ch) {
            float4 v = *(const float4*)(fb + ch * HW);
            *(float4*)&fmL[ch][rel * 128 + xc] =
                make_float4(v.x + 10.0f, v.y + 10.0f, v.z + 10.0f, v.w + 10.0f);
        }
        stw[0][tid] = ((const uint32_t*)(gsrc + (size_t)img * HW + y * 128))[tid & 31];
    }
    __syncthreads();

    // ---- kw[9][4] into registers (once), then PIN --------------------------
    const bool compute = ((unsigned)y < 128u) && (y >= r0 - 4) && (y < r0 + 12);
    float kw[9][4];
    #pragma unroll
    for (int k = 0; k < 9; ++k)
        #pragma unroll
        for (int j = 0; j < 4; ++j) kw[k][j] = 0.0f;
    if (compute) {
        float c0[4], c1[4], c2[4];
        {
            float4 a = *(const float4*)&fmL[0][rel * 128 + xc];
            c0[0] = a.x; c0[1] = a.y; c0[2] = a.z; c0[3] = a.w;
            a = *(const float4*)&fmL[1][rel * 128 + xc];
            c1[0] = a.x; c1[1] = a.y; c1[2] = a.z; c1[3] = a.w;
            a = *(const float4*)&fmL[2][rel * 128 + xc];
            c2[0] = a.x; c2[1] = a.y; c2[2] = a.z; c2[3] = a.w;
        }
        #pragma unroll
        for (int g = 0; g < 3; ++g) {
            const int dy = g - 1;
            const int ny = y + dy;
            if ((unsigned)ny < 128u) {
                const int rr = (rel + dy) * 128;
                float rv0[6], rv1[6], rv2[6];
                {
                    float4 m = *(const float4*)&fmL[0][rr + xc];
                    rv0[1] = m.x; rv0[2] = m.y; rv0[3] = m.z; rv0[4] = m.w;
                    rv0[0] = (xc > 0) ? fmL[0][rr + xc - 1] : 0.0f;
                    rv0[5] = (xc < 124) ? fmL[0][rr + xc + 4] : 0.0f;
                    m = *(const float4*)&fmL[1][rr + xc];
                    rv1[1] = m.x; rv1[2] = m.y; rv1[3] = m.z; rv1[4] = m.w;
                    rv1[0] = (xc > 0) ? fmL[1][rr + xc - 1] : 0.0f;
                    rv1[5] = (xc < 124) ? fmL[1][rr + xc + 4] : 0.0f;
                    m = *(const float4*)&fmL[2][rr + xc];
                    rv2[1] = m.x; rv2[2] = m.y; rv2[3] = m.z; rv2[4] = m.w;
                    rv2[0] = (xc > 0) ? fmL[2][rr + xc - 1] : 0.0f;
                    rv2[5] = (xc < 124) ? fmL[2][rr + xc + 4] : 0.0f;
                }
                #pragma unroll
                for (int dxi = 0; dxi < 3; ++dxi) {
                    const int dx = dxi - 1, k = g * 3 + dxi;
                    const float sp = (float)(dy * dy + dx * dx) / 1800.0f;
                    #pragma unroll
                    for (int j = 0; j < 4; ++j) {
                        const int nx = xc + j + dx;
                        if ((unsigned)nx < 128u) {
                            const int m = j + dx + 1;
                            float d0 = rv0[m] - c0[j];
                            float d1 = rv1[m] - c1[j];
                            float d2 = rv2[m] - c2[j];
                            float ss = d0 * d0;
                            ss = ss + d1 * d1;
                            ss = ss + d2 * d2;
                            float color = (-ss) / 0.5f;
                            kw[k][j] = 3.0f * expf(color - sp);
                        }
                    }
                }
            }
        }
    }
    // Opaque pin: forbids rematerialization — kw MUST stay in VGPRs.
    #pragma unroll
    for (int k = 0; k < 9; ++k)
        #pragma unroll
        for (int j = 0; j < 4; ++j) asm volatile("" : "+v"(kw[k][j]));

    // ---- 5 sweeps, taps from pinned registers ------------------------------
    const float l45 = 0.7985076962177716f;  // -log(0.45f)
    const float l55 = 0.5978370007556204f;  // -log(0.55f)
    float* om = out + NM + (size_t)img * HW;
    int sA = 0, cnt = 0;
    #pragma unroll
    for (int s = 0; s < 5; ++s) {
        const int lo = (r0 - 4 + s < 0) ? 0 : r0 - 4 + s;
        const int hi = (r0 + 12 - s > 128) ? 128 : r0 + 12 - s;
        const bool last = (s == 4);
        const bool act = compute && (y >= lo) && (y < hi);
        if (act) {
            unsigned char rb[3][6];
            const uint32_t* sw = &stw[sA][0];
            #pragma unroll
            for (int r = 0; r < 3; ++r) {
                const int ry = y + r - 1;
                if ((unsigned)ry < 128u) {
                    const int base = (ry - w0) * 32 + (xc >> 2);
                    const uint32_t wm = (xc > 0) ? sw[base - 1] : 0u;
                    const uint32_t wc = sw[base];
                    const uint32_t wp = (xc < 124) ? sw[base + 1] : 0u;
                    rb[r][0] = wm >> 24;
                    rb[r][1] = wc & 0xff; rb[r][2] = (wc >> 8) & 0xff;
                    rb[r][3] = (wc >> 16) & 0xff; rb[r][4] = wc >> 24;
                    rb[r][5] = wp & 0xff;
                } else {
                    #pragma unroll
                    for (int m = 0; m < 6; ++m) rb[r][m] = 0;  // kw==0 there
                }
            }
            float a0[4] = {0.f, 0.f, 0.f, 0.f}, a1[4] = {0.f, 0.f, 0.f, 0.f};
            #pragma unroll
            for (int k = 0; k < 9; ++k) {
                #pragma unroll
                for (int j = 0; j < 4; ++j) {
                    const float kwv = kw[k][j];
                    const unsigned char sq = rb[k / 3][j + (k % 3)];
                    const float lx1 = (sq & 1) ? l55 : l45;
                    const float lx0 = (sq & 2) ? l55 : l45;
                    const float t1 = lx1 * kwv;   // mul then add (numpy order)
                    const float t0 = lx0 * kwv;
                    a1[j] = a1[j] + t1;
                    a0[j] = a0[j] + t0;
                }
            }
            // epilogue (proven exact sequence)
            uint32_t ow = 0;
            float mv[4];
            int c1 = 0;
            #pragma unroll
            for (int j = 0; j < 4; ++j) {
                const unsigned char sc = rb[1][j + 1];
                const float tval = (sc & 4) ? 1.0f : 0.0f;
                const float e1 = expf(-a1[j]);
                const float e0 = expf(-a0[j]);
                const float m1 = e1 * tval;
                const float f1 = m1 + 1e-6f;
                const float f0 = e0 + 1e-6f;
                const float den = f0 + f1;
                const float r1 = f1 / den;
                const float r0v = f0 / den;
                const int s1 = (r1 > 0.5f) ? 1 : 0;
                const int s0 = (r0v > 0.5f) ? 1 : 0;
                mv[j] = (float)s1;
                c1 += s1;
                ow |= (uint32_t)(s1 | (s0 << 1) | (sc & 4)) << (8 * j);
            }
            if (!last) {
                stw[sA ^ 1][tid] = ow;
            } else if (FIRST) {
                ((uint32_t*)(gdst2 + (size_t)img * HW))[y * 32 + (xc >> 2)] = ow;
            } else {
                *(float4*)(om + y * 128 + xc) = make_float4(mv[0], mv[1], mv[2], mv[3]);
                cnt = c1;
            }
        }
        __syncthreads();
        sA ^= 1;
    }

    // ---- phase B tail: counts + valid (proven ticket, 1024 blocks) ---------
    if (!FIRST) {
        int* cred = (int*)&fmL[0][0];
        cred[tid] = cnt;
        if (tid < 448) cred[576 + tid] = 0;   // pad to 1024
        __syncthreads();
        for (int off = 512; off > 0; off >>= 1) {
            if (tid < off) cred[tid] += cred[tid + off];
            __syncthreads();
        }
        int* flag = (int*)&stw[0][0];
        if (tid == 0) {
            atomicAdd(&counters[img], cred[0]);
            __threadfence();
            int old = atomicAdd(&counters[NI], 1);
            flag[0] = (old == 1023) ? 1 : 0;
        }
        __syncthreads();
        if (flag[0] && tid < NI) {
            int c = atomicAdd(&counters[tid], 0);
            // 16384*0.05 = 819.2, 16384*0.95 = 15564.8; counts are integers
            out[NM + (size_t)NI * HW + tid] = (c >= 820 && c <= 15564) ? 1.0f : 0.0f;
        }
    }
}

extern "C" void kernel_launch(void* const* d_in, const int* in_sizes, int n_in,
                              void* d_out, int out_size, void* d_ws, size_t ws_size,
                              hipStream_t stream) {
    const float* seg = (const float*)d_in[0];
    const float* cate_scores = (const float*)d_in[1];
    const float* feat = (const float*)d_in[2];
    const float* x = (const float*)d_in[3];
    const float* targets = (const float*)d_in[4];
    const int* labels = (const int*)d_in[5];
    float* out = (float*)d_out;
    char* ws = (char*)d_ws;

    unsigned char* state = (unsigned char*)(ws + OFF_STATE);
    unsigned char* state2 = (unsigned char*)(ws + OFF_STATE2);
    unsigned long long* packed = (unsigned long long*)(ws + OFF_PACKED);
    float* diouT = (float*)(ws + OFF_DIOUT);
    float* compm = (float*)(ws + OFF_COMPM);
    int* counters = (int*)(ws + OFF_CNT);

    setup_kernel<<<512, 256, 0, stream>>>(seg, x, targets, state, packed, counters);
    diou_compm_kernel<<<NM, 256, 0, stream>>>(packed, labels, diouT, compm);
    crf5_kernel<true><<<1024, 576, 0, stream>>>(feat, cate_scores, diouT, compm,
                                                state, state2, out, counters);
    crf5_kernel<false><<<1024, 576, 0, stream>>>(feat, cate_scores, diouT, compm,
                                                 state2, nullptr, out, counters);
}

// Round 12
// 214.108 us; speedup vs baseline: 1.2186x; 1.2186x over previous
//
#include <hip/hip_runtime.h>
#include <stdint.h>

#define HW 16384
#define NI 64
#define NM 256
#define WORDS 256

// ws layout (~3 MB used)
#define OFF_STATE2 (1u << 20)    // 1 MB state bytes (iter-5 handoff A->B)
#define OFF_PACKED (2u << 20)    // 512 KB bit-packed masks [word][mask]
#define OFF_DIOUT  0x280000u     // 256 KB diou transposed diouT[col][row]
#define OFF_COMPM  0x2C0000u
#define OFF_CNT    0x2C1000u     // 64 counters + done ticket at [64]

// ---------------- fused diou + compm (proven) -------------------------------
__global__ __launch_bounds__(256) void diou_compm_kernel(
    const unsigned long long* __restrict__ packed, const int* __restrict__ labels,
    float* __restrict__ diouT, float* __restrict__ compm) {
    #pragma clang fp contract(off)
    __shared__ unsigned long long colj[WORDS];
    __shared__ float red[NM];
    const int j = blockIdx.x, i = threadIdx.x;
    colj[i] = packed[i * NM + j];
    __syncthreads();
    int inter = 0, si = 0, sj = 0;
    for (int w = 0; w < WORDS; ++w) {
        unsigned long long a = colj[w];
        unsigned long long b = packed[w * NM + i];
        inter += __popcll(a & b);
        sj += __popcll(a);
        si += __popcll(b);
    }
    float d = 0.0f;
    if (j > i && labels[i] == labels[j]) {
        float u = (float)(si + sj - inter);   // exact integers in f32
        d = (float)inter / u;
    }
    diouT[j * NM + i] = d;
    red[i] = d;
    __syncthreads();
    for (int off = 128; off > 0; off >>= 1) {
        if (i < off) red[i] = fmaxf(red[i], red[i + off]);
        __syncthreads();
    }
    if (i == 0) {
        float m = red[0];
        float t = m * m;
        compm[j] = expf(-2.0f * t);
    }
}

// ---------------- CRF: 5 iters/launch (R9-proven body, 65.5 us) -------------
// 512 blocks = 64 img x 8 tiles of 16 rows; 832 threads = 26-row window x 32
// quads. LDS planes (symmetry: kw[k][p]==kw[8-k][p+off(k)], exact; center
// == 3.0f exactly; OOB kw == 0 exactly). Sweep s computes rows
// [max(0,r0-4+s), min(128,r0+20-s)) — halo argument proven bit-exact.
// A (FIRST): pack masks + iter-0 state from x,targets + counters zero; writes
//            iter-5 state to gdst2. B: coef prologue + iters 6-10 + tail.
template <bool FIRST>
__global__ __launch_bounds__(832, 6) void crf5_kernel(
    const float* __restrict__ feat, const float* __restrict__ scores,
    const float* __restrict__ diouT, const float* __restrict__ compm,
    const float* __restrict__ seg, unsigned long long* __restrict__ packed,
    const float* __restrict__ x, const float* __restrict__ targets,
    unsigned char* __restrict__ state2, float* __restrict__ out,
    int* __restrict__ counters) {
    #pragma clang fp contract(off)
    __shared__ float plane[4 * 3328];     // 53248 B: planes k=0..3, 26 rows
    __shared__ uint32_t stw[2][26 * 32];  // 6656 B ping-pong state
    const int tid = threadIdx.x, bid = blockIdx.x;
    const int img = bid >> 3, r0 = (bid & 7) * 16;
    const int w0 = r0 - 5;
    const int rel = tid >> 5;             // 0..25
    const int xc = (tid & 31) * 4;
    const int y = w0 + rel;

    if (FIRST) {
        // ---- pack (fused; identical ballot body to proven setup) ----------
        const int wave = tid >> 6, lane = tid & 63;
        const int gw = bid * 13 + wave;          // 512*13 = 6656 waves
        if (gw < 4096) {
            for (int t = 0; t < 16; ++t) {
                int gwi = gw * 16 + t;           // [0, 65536)
                int i = gwi >> 8, w = gwi & 255;
                float v = seg[(size_t)i * HW + w * 64 + lane];
                unsigned long long m = __ballot(v > 0.5f);
                if (lane == 0) packed[w * NM + i] = m;
            }
        }
        if (bid == 0 && tid < NI + 1) counters[tid] = 0;  // [64] = ticket
    } else {
        // ---- coef prologue (blocks 0..255) — plane as scratch -------------
        if (bid < NM) {
            float* red = plane;
            if (tid < NM) {
                float d = diouT[bid * NM + tid];
                float dd = d * d;
                float dec = expf(-2.0f * dd);
                red[tid] = dec / compm[tid];
            }
            __syncthreads();
            for (int off = 128; off > 0; off >>= 1) {
                if (tid < off) red[tid] = fminf(red[tid], red[tid + off]);
                __syncthreads();
            }
            if (tid == 0) out[bid] = scores[bid] * red[0];
            __syncthreads();
        }
    }

    // ---- plane precompute (R9-proven verbatim) -----------------------------
    {
        if ((unsigned)y < 128u) {
            const float* fb = feat + (size_t)img * 3 * HW;
            const int pp = y * 128 + xc;
            float4 cv0 = *(const float4*)&fb[pp];
            float4 cv1 = *(const float4*)&fb[HW + pp];
            float4 cv2 = *(const float4*)&fb[2 * HW + pp];
            float c0[4] = {cv0.x + 10.0f, cv0.y + 10.0f, cv0.z + 10.0f, cv0.w + 10.0f};
            float c1[4] = {cv1.x + 10.0f, cv1.y + 10.0f, cv1.z + 10.0f, cv1.w + 10.0f};
            float c2[4] = {cv2.x + 10.0f, cv2.y + 10.0f, cv2.z + 10.0f, cv2.w + 10.0f};
            #pragma unroll
            for (int k = 0; k < 4; ++k) {
                const int dy = (k < 3) ? -1 : 0;
                const int dx = (k < 3) ? (k - 1) : -1;
                const int ny = y + dy;
                float res[4];
                #pragma unroll
                for (int j = 0; j < 4; ++j) {
                    const int nx = xc + j + dx;
                    float kwv = 0.0f;
                    if ((unsigned)ny < 128u && (unsigned)nx < 128u) {
                        const int qq = ny * 128 + nx;
                        float u0 = fb[qq] + 10.0f;
                        float u1 = fb[HW + qq] + 10.0f;
                        float u2 = fb[2 * HW + qq] + 10.0f;
                        float d0 = u0 - c0[j], d1 = u1 - c1[j], d2 = u2 - c2[j];
                        float ss = d0 * d0;
                        ss = ss + d1 * d1;
                        ss = ss + d2 * d2;
                        float color = (-ss) / 0.5f;
                        float sp = (float)(dy * dy + dx * dx) / 1800.0f;
                        kwv = 3.0f * expf(color - sp);
                    }
                    res[j] = kwv;
                }
                *(float4*)&plane[k * 3328 + rel * 128 + xc] =
                    make_float4(res[0], res[1], res[2], res[3]);
            }
        }
        // window state: A computes iter-0 from x,targets (exact setup formula);
        // B loads the iter-5 handoff.
        if ((unsigned)y < 128u) {
            if (FIRST) {
                const int gp = (int)((size_t)img * HW) + y * 128 + xc;
                const float4 xv = *(const float4*)(x + gp);
                const float4 tv = *(const float4*)(targets + gp);
                float xs[4] = {xv.x, xv.y, xv.z, xv.w};
                float ts[4] = {tv.x, tv.y, tv.z, tv.w};
                uint32_t st = 0;
                #pragma unroll
                for (int j = 0; j < 4; ++j) {
                    float xt = xs[j] * ts[j];
                    int b1 = (xt > 0.5f) ? 1 : 0;
                    int tb = (ts[j] > 0.5f) ? 1 : 0;
                    st |= (uint32_t)(b1 | ((b1 ^ 1) << 1) | (tb << 2)) << (8 * j);
                }
                stw[0][tid] = st;
            } else {
                stw[0][tid] =
                    ((const uint32_t*)(state2 + (size_t)img * HW + y * 128))[tid & 31];
            }
        }
    }
    __syncthreads();

    // ---- kw fragments (R9-proven verbatim; compiler re-reads LDS) ----------
    const bool compute = ((unsigned)y < 128u) && (y >= r0 - 4) && (y < r0 + 20);
    float kw[9][4];
    if (compute) {
        #pragma unroll
        for (int k = 0; k < 4; ++k) {
            float4 v = *(const float4*)&plane[k * 3328 + rel * 128 + xc];
            kw[k][0] = v.x; kw[k][1] = v.y; kw[k][2] = v.z; kw[k][3] = v.w;
        }
        kw[4][0] = kw[4][1] = kw[4][2] = kw[4][3] = 3.0f;  // center, exact
        #pragma unroll
        for (int k = 5; k < 9; ++k) {
            const int dy = k / 3 - 1, dx = k % 3 - 1;
            const int ry = y + dy, prow = ry - w0;
            #pragma unroll
            for (int j = 0; j < 4; ++j) {
                const int nx = xc + j + dx;
                kw[k][j] = ((unsigned)ry < 128u && (unsigned)nx < 128u)
                               ? plane[(8 - k) * 3328 + prow * 128 + nx]
                               : 0.0f;
            }
        }
    }

    // ---- 5 sweeps (R9-proven verbatim) -------------------------------------
    const float l45 = 0.7985076962177716f;  // -log(0.45f)
    const float l55 = 0.5978370007556204f;  // -log(0.55f)
    float* om = out + NM + (size_t)img * HW;
    int sA = 0, cnt = 0;
    for (int s = 0; s < 5; ++s) {
        const int lo = (r0 - 4 + s < 0) ? 0 : r0 - 4 + s;
        const int hi = (r0 + 20 - s > 128) ? 128 : r0 + 20 - s;
        const bool last = (s == 4);
        const bool act = compute && (y >= lo) && (y < hi);
        if (act) {
            unsigned char rb[3][6];
            const uint32_t* sw = &stw[sA][0];
            #pragma unroll
            for (int r = 0; r < 3; ++r) {
                const int ry = y + r - 1;
                if ((unsigned)ry < 128u) {
                    const int base = (ry - w0) * 32 + (xc >> 2);
                    const uint32_t wm = (xc > 0) ? sw[base - 1] : 0u;
                    const uint32_t wc = sw[base];
                    const uint32_t wp = (xc < 124) ? sw[base + 1] : 0u;
                    rb[r][0] = wm >> 24;
                    rb[r][1] = wc & 0xff; rb[r][2] = (wc >> 8) & 0xff;
                    rb[r][3] = (wc >> 16) & 0xff; rb[r][4] = wc >> 24;
                    rb[r][5] = wp & 0xff;
                } else {
                    #pragma unroll
                    for (int m = 0; m < 6; ++m) rb[r][m] = 0;  // kw==0 there
                }
            }
            float a0[4] = {0.f, 0.f, 0.f, 0.f}, a1[4] = {0.f, 0.f, 0.f, 0.f};
            #pragma unroll
            for (int k = 0; k < 9; ++k) {
                #pragma unroll
                for (int j = 0; j < 4; ++j) {
                    const float kwv = kw[k][j];
                    const unsigned char sq = rb[k / 3][j + (k % 3)];
                    const float lx1 = (sq & 1) ? l55 : l45;
                    const float lx0 = (sq & 2) ? l55 : l45;
                    const float t1 = lx1 * kwv;   // mul then add (numpy order)
                    const float t0 = lx0 * kwv;
                    a1[j] = a1[j] + t1;
                    a0[j] = a0[j] + t0;
                }
            }
            // epilogue (proven exact sequence)
            uint32_t ow = 0;
            float mv[4];
            int c1 = 0;
            #pragma unroll
            for (int j = 0; j < 4; ++j) {
                const unsigned char sc = rb[1][j + 1];
                const float tval = (sc & 4) ? 1.0f : 0.0f;
                const float e1 = expf(-a1[j]);
                const float e0 = expf(-a0[j]);
                const float m1 = e1 * tval;
                const float f1 = m1 + 1e-6f;
                const float f0 = e0 + 1e-6f;
                const float den = f0 + f1;
                const float r1 = f1 / den;
                const float r0v = f0 / den;
                const int s1 = (r1 > 0.5f) ? 1 : 0;
                const int s0 = (r0v > 0.5f) ? 1 : 0;
                mv[j] = (float)s1;
                c1 += s1;
                ow |= (uint32_t)(s1 | (s0 << 1) | (sc & 4)) << (8 * j);
            }
            if (!last) {
                stw[sA ^ 1][(y - w0) * 32 + (xc >> 2)] = ow;
            } else if (FIRST) {
                ((uint32_t*)(state2 + (size_t)img * HW))[y * 32 + (xc >> 2)] = ow;
            } else {
                *(float4*)(om + y * 128 + xc) = make_float4(mv[0], mv[1], mv[2], mv[3]);
                cnt = c1;
            }
        }
        __syncthreads();
        sA ^= 1;
    }

    // ---- phase B tail: counts + valid (proven ticket) ----------------------
    if (!FIRST) {
        int* cred = (int*)plane;
        cred[tid] = cnt;
        if (tid < 192) cred[832 + tid] = 0;   // pad to 1024
        __syncthreads();
        for (int off = 512; off > 0; off >>= 1) {
            if (tid < off) cred[tid] += cred[tid + off];
            __syncthreads();
        }
        int* flag = (int*)&stw[0][0];
        if (tid == 0) {
            atomicAdd(&counters[img], cred[0]);
            __threadfence();
            int old = atomicAdd(&counters[NI], 1);
            flag[0] = (old == 511) ? 1 : 0;
        }
        __syncthreads();
        if (flag[0] && tid < NI) {
            int c = atomicAdd(&counters[tid], 0);
            // 16384*0.05 = 819.2, 16384*0.95 = 15564.8; counts are integers
            out[NM + (size_t)NI * HW + tid] = (c >= 820 && c <= 15564) ? 1.0f : 0.0f;
        }
    }
}

extern "C" void kernel_launch(void* const* d_in, const int* in_sizes, int n_in,
                              void* d_out, int out_size, void* d_ws, size_t ws_size,
                              hipStream_t stream) {
    const float* seg = (const float*)d_in[0];
    const float* cate_scores = (const float*)d_in[1];
    const float* feat = (const float*)d_in[2];
    const float* x = (const float*)d_in[3];
    const float* targets = (const float*)d_in[4];
    const int* labels = (const int*)d_in[5];
    float* out = (float*)d_out;
    char* ws = (char*)d_ws;

    unsigned char* state2 = (unsigned char*)(ws + OFF_STATE2);
    unsigned long long* packed = (unsigned long long*)(ws + OFF_PACKED);
    float* diouT = (float*)(ws + OFF_DIOUT);
    float* compm = (float*)(ws + OFF_COMPM);
    int* counters = (int*)(ws + OFF_CNT);

    // Node 1: CRF iters 1-5 + fused mask-pack + iter-0 state + counter zero
    crf5_kernel<true><<<512, 832, 0, stream>>>(feat, cate_scores, diouT, compm,
                                               seg, packed, x, targets, state2,
                                               out, counters);
    // Node 2: NMS diou + compm (needs packed from node 1)
    diou_compm_kernel<<<NM, 256, 0, stream>>>(packed, labels, diouT, compm);
    // Node 3: coef + CRF iters 6-10 + masks/counts/valid
    crf5_kernel<false><<<512, 832, 0, stream>>>(feat, cate_scores, diouT, compm,
                                                seg, packed, x, targets, state2,
                                                out, counters);
}

// Round 13
// 189.179 us; speedup vs baseline: 1.3791x; 1.1318x over previous
//
#include <hip/hip_runtime.h>
#include <stdint.h>

#define HW 16384
#define NI 64
#define NM 256
#define WORDS 256

// plane padding: stride 136 floats/row (4 guard cols each side, zeroed)
#define PR 136
#define PSZ (26 * PR)   // 3536 floats per plane
// state padding: stride 34 words/row (1 guard word each side, zeroed)
#define SR 34

// ws layout (~3 MB used)
#define OFF_STATE2 (1u << 20)    // 1 MB state bytes (iter-5 handoff A->B)
#define OFF_PACKED (2u << 20)    // 512 KB bit-packed masks [word][mask]
#define OFF_DIOUT  0x280000u     // 256 KB diou transposed diouT[col][row]
#define OFF_COMPM  0x2C0000u
#define OFF_CNT    0x2C1000u     // 64 counters + done ticket at [64]

// ---------------- fused diou + compm (proven) -------------------------------
__global__ __launch_bounds__(256) void diou_compm_kernel(
    const unsigned long long* __restrict__ packed, const int* __restrict__ labels,
    float* __restrict__ diouT, float* __restrict__ compm) {
    #pragma clang fp contract(off)
    __shared__ unsigned long long colj[WORDS];
    __shared__ float red[NM];
    const int j = blockIdx.x, i = threadIdx.x;
    colj[i] = packed[i * NM + j];
    __syncthreads();
    int inter = 0, si = 0, sj = 0;
    for (int w = 0; w < WORDS; ++w) {
        unsigned long long a = colj[w];
        unsigned long long b = packed[w * NM + i];
        inter += __popcll(a & b);
        sj += __popcll(a);
        si += __popcll(b);
    }
    float d = 0.0f;
    if (j > i && labels[i] == labels[j]) {
        float u = (float)(si + sj - inter);   // exact integers in f32
        d = (float)inter / u;
    }
    diouT[j * NM + i] = d;
    red[i] = d;
    __syncthreads();
    for (int off = 128; off > 0; off >>= 1) {
        if (i < off) red[i] = fmaxf(red[i], red[i + off]);
        __syncthreads();
    }
    if (i == 0) {
        float m = red[0];
        float t = m * m;
        compm[j] = expf(-2.0f * t);
    }
}

// ---------------- CRF: 5 iters/launch, branchless padded sweeps -------------
// 512 blocks = 64 img x 8 tiles of 16 rows; 832 threads = 26-row window x 32
// quads. Planes k=0..3 in LDS (mirror identity kw[k][p]==kw[8-k][p+off(k)],
// exact in f32; center==3.0f; OOB kw==0 exactly via underflow). Zero-padded
// guards remove ALL tap guards: a += lx*0 == a exactly. Sweep s computes rows
// [max(0,r0-4+s), min(128,r0+20-s)) — halo argument proven bit-exact.
// Early-exit: if no active word changed, all later sweeps are identical
// (deterministic map on unchanged input; checked range covers future reads).
template <bool FIRST>
__global__ __launch_bounds__(832, 6) void crf5_kernel(
    const float* __restrict__ feat, const float* __restrict__ scores,
    const float* __restrict__ diouT, const float* __restrict__ compm,
    const float* __restrict__ seg, unsigned long long* __restrict__ packed,
    const float* __restrict__ x, const float* __restrict__ targets,
    unsigned char* __restrict__ state2, float* __restrict__ out,
    int* __restrict__ counters) {
    #pragma clang fp contract(off)
    __shared__ float plane[4 * PSZ];      // 56576 B
    __shared__ uint32_t stw[2][26 * SR];  // 7072 B
    __shared__ int chg;                   // total 63652 B < 64 KiB
    const int tid = threadIdx.x, bid = blockIdx.x;
    const int img = bid >> 3, r0 = (bid & 7) * 16;
    const int w0 = r0 - 5;
    const int rel = tid >> 5;             // 0..25
    const int q = tid & 31;
    const int xc = q * 4;
    const int y = w0 + rel;
    const bool inimg = (unsigned)y < 128u;

    if (FIRST) {
        // ---- pack (fused; proven ballot body) -----------------------------
        const int wave = tid >> 6, lane = tid & 63;
        const int gw = bid * 13 + wave;          // 6656 waves; 4096 used
        if (gw < 4096) {
            for (int t = 0; t < 16; ++t) {
                int gwi = gw * 16 + t;           // [0, 65536)
                int i = gwi >> 8, w = gwi & 255;
                float v = seg[(size_t)i * HW + w * 64 + lane];
                unsigned long long m = __ballot(v > 0.5f);
                if (lane == 0) packed[w * NM + i] = m;
            }
        }
        if (bid == 0 && tid < NI + 1) counters[tid] = 0;  // [64] = ticket
    } else {
        // ---- coef prologue (blocks 0..255) — plane as scratch -------------
        if (bid < NM) {
            float* red = plane;
            if (tid < NM) {
                float d = diouT[bid * NM + tid];
                float dd = d * d;
                float dec = expf(-2.0f * dd);
                red[tid] = dec / compm[tid];
            }
            __syncthreads();
            for (int off = 128; off > 0; off >>= 1) {
                if (tid < off) red[tid] = fminf(red[tid], red[tid + off]);
                __syncthreads();
            }
            if (tid == 0) out[bid] = scores[bid] * red[0];
            __syncthreads();
        }
    }

    // ---- plane precompute (padded, zero-filled; proven float sequence) -----
    {
        const float* fb = feat + (size_t)img * 3 * HW;
        float c0[4], c1[4], c2[4];
        if (inimg) {
            const int pp = y * 128 + xc;
            float4 cv0 = *(const float4*)&fb[pp];
            float4 cv1 = *(const float4*)&fb[HW + pp];
            float4 cv2 = *(const float4*)&fb[2 * HW + pp];
            c0[0]=cv0.x+10.0f; c0[1]=cv0.y+10.0f; c0[2]=cv0.z+10.0f; c0[3]=cv0.w+10.0f;
            c1[0]=cv1.x+10.0f; c1[1]=cv1.y+10.0f; c1[2]=cv1.z+10.0f; c1[3]=cv1.w+10.0f;
            c2[0]=cv2.x+10.0f; c2[1]=cv2.y+10.0f; c2[2]=cv2.z+10.0f; c2[3]=cv2.w+10.0f;
        }
        #pragma unroll
        for (int k = 0; k < 4; ++k) {
            const int dy = (k < 3) ? -1 : 0;
            const int dx = (k < 3) ? (k - 1) : -1;
            float res[4] = {0.0f, 0.0f, 0.0f, 0.0f};
            if (inimg) {
                const int ny = y + dy;
                if ((unsigned)ny < 128u) {
                    #pragma unroll
                    for (int j = 0; j < 4; ++j) {
                        const int nx = xc + j + dx;
                        if ((unsigned)nx < 128u) {
                            const int qq = ny * 128 + nx;
                            float u0 = fb[qq] + 10.0f;
                            float u1 = fb[HW + qq] + 10.0f;
                            float u2 = fb[2 * HW + qq] + 10.0f;
                            float d0 = u0 - c0[j], d1 = u1 - c1[j], d2 = u2 - c2[j];
                            float ss = d0 * d0;
                            ss = ss + d1 * d1;
                            ss = ss + d2 * d2;
                            float color = (-ss) / 0.5f;
                            float sp = (float)(dy * dy + dx * dx) / 1800.0f;
                            res[j] = 3.0f * expf(color - sp);
                        }
                    }
                }
            }
            *(float4*)&plane[k * PSZ + rel * PR + 4 + xc] =
                make_float4(res[0], res[1], res[2], res[3]);
            if (q == 0)
                *(float4*)&plane[k * PSZ + rel * PR + 0] = make_float4(0, 0, 0, 0);
            if (q == 31)
                *(float4*)&plane[k * PSZ + rel * PR + 132] = make_float4(0, 0, 0, 0);
        }
        // state: A computes iter-0 from x,targets (exact formula); B loads.
        uint32_t st = 0;
        if (inimg) {
            if (FIRST) {
                const size_t gp = (size_t)img * HW + y * 128 + xc;
                const float4 xv = *(const float4*)(x + gp);
                const float4 tv = *(const float4*)(targets + gp);
                float xs[4] = {xv.x, xv.y, xv.z, xv.w};
                float ts[4] = {tv.x, tv.y, tv.z, tv.w};
                #pragma unroll
                for (int j = 0; j < 4; ++j) {
                    float xt = xs[j] * ts[j];
                    int b1 = (xt > 0.5f) ? 1 : 0;
                    int tb = (ts[j] > 0.5f) ? 1 : 0;
                    st |= (uint32_t)(b1 | ((b1 ^ 1) << 1) | (tb << 2)) << (8 * j);
                }
            } else {
                st = ((const uint32_t*)(state2 + (size_t)img * HW + y * 128))[q];
            }
        }
        stw[0][rel * SR + 1 + q] = st;
        if (!inimg) stw[1][rel * SR + 1 + q] = 0;
        if (q == 0)  { stw[0][rel * SR + 0]  = 0; stw[1][rel * SR + 0]  = 0; }
        if (q == 31) { stw[0][rel * SR + 33] = 0; stw[1][rel * SR + 33] = 0; }
    }
    __syncthreads();

    // ---- 5 sweeps: branchless taps, early-exit on convergence --------------
    const float l45 = 0.7985076962177716f;  // -log(0.45f)
    const float l55 = 0.5978370007556204f;  // -log(0.55f)
    const bool compute = inimg && (y >= r0 - 4) && (y < r0 + 20);
    const int lane = tid & 63;
    const int rbase = rel * PR + 4 + xc;
    const int sbase = rel * SR + 1 + q;
    int cur = 0;
    for (int s = 0; s < 5; ++s) {
        if (tid == 0) chg = 0;
        __syncthreads();
        const int lo = (r0 - 4 + s < 0) ? 0 : r0 - 4 + s;
        const int hi = (r0 + 20 - s > 128) ? 128 : r0 + 20 - s;
        const bool act = compute && (y >= lo) && (y < hi);
        bool changed = false;
        if (act) {
            const uint32_t* sw = &stw[cur][0];
            // per-row lx tables from 9 padded word reads (no guards)
            float lx1r[3][6], lx0r[3][6];
            uint32_t wcen = 0;
            #pragma unroll
            for (int r = 0; r < 3; ++r) {
                const int base = sbase + (r - 1) * SR;
                const uint32_t wm = sw[base - 1];
                const uint32_t wc = sw[base];
                const uint32_t wp = sw[base + 1];
                if (r == 1) wcen = wc;
                unsigned char b[6];
                b[0] = wm >> 24;
                b[1] = wc & 0xff; b[2] = (wc >> 8) & 0xff;
                b[3] = (wc >> 16) & 0xff; b[4] = wc >> 24;
                b[5] = wp & 0xff;
                #pragma unroll
                for (int m = 0; m < 6; ++m) {
                    lx1r[r][m] = (b[m] & 1) ? l55 : l45;
                    lx0r[r][m] = (b[m] & 2) ? l55 : l45;
                }
            }
            // kw gather: 7 x b128 + 3 scalars via mirror identity
            float4 p0a = *(const float4*)&plane[0 * PSZ + rbase];
            float4 p1a = *(const float4*)&plane[1 * PSZ + rbase];
            float4 p2a = *(const float4*)&plane[2 * PSZ + rbase];
            float4 p3a = *(const float4*)&plane[3 * PSZ + rbase];
            float4 p0b = *(const float4*)&plane[0 * PSZ + rbase + PR];
            float4 p1b = *(const float4*)&plane[1 * PSZ + rbase + PR];
            float4 p2b = *(const float4*)&plane[2 * PSZ + rbase + PR];
            float s5 = plane[3 * PSZ + rbase + 4];
            float s6 = plane[2 * PSZ + rbase + PR - 1];
            float s8 = plane[0 * PSZ + rbase + PR + 4];
            const float kw[9][4] = {
                {p0a.x, p0a.y, p0a.z, p0a.w},
                {p1a.x, p1a.y, p1a.z, p1a.w},
                {p2a.x, p2a.y, p2a.z, p2a.w},
                {p3a.x, p3a.y, p3a.z, p3a.w},
                {3.0f, 3.0f, 3.0f, 3.0f},
                {p3a.y, p3a.z, p3a.w, s5},
                {s6, p2b.x, p2b.y, p2b.z},
                {p1b.x, p1b.y, p1b.z, p1b.w},
                {p0b.y, p0b.z, p0b.w, s8}};
            float a0[4] = {0.f, 0.f, 0.f, 0.f}, a1[4] = {0.f, 0.f, 0.f, 0.f};
            #pragma unroll
            for (int k = 0; k < 9; ++k) {
                const int r = k / 3, m0 = k % 3;
                #pragma unroll
                for (int j = 0; j < 4; ++j) {
                    const float kwv = kw[k][j];
                    const float t1 = lx1r[r][j + m0] * kwv;  // mul then add
                    const float t0 = lx0r[r][j + m0] * kwv;
                    a1[j] = a1[j] + t1;
                    a0[j] = a0[j] + t0;
                }
            }
            // epilogue (proven exact sequence)
            uint32_t ow = 0;
            #pragma unroll
            for (int j = 0; j < 4; ++j) {
                const unsigned char sc = (wcen >> (8 * j)) & 0xffu;
                const float tval = (sc & 4) ? 1.0f : 0.0f;
                const float e1 = expf(-a1[j]);
                const float e0 = expf(-a0[j]);
                const float m1 = e1 * tval;
                const float f1 = m1 + 1e-6f;
                const float f0 = e0 + 1e-6f;
                const float den = f0 + f1;
                const float r1 = f1 / den;
                const float r0v = f0 / den;
                const int s1 = (r1 > 0.5f) ? 1 : 0;
                const int s0 = (r0v > 0.5f) ? 1 : 0;
                ow |= (uint32_t)(s1 | (s0 << 1) | (sc & 4)) << (8 * j);
            }
            stw[cur ^ 1][sbase] = ow;
            changed = (ow != wcen);
        }
        unsigned long long bal = __ballot(changed);
        if (lane == 0 && bal) atomicOr(&chg, 1);
        __syncthreads();
        if (chg == 0) break;   // converged: all later sweeps identical (exact)
        cur ^= 1;
    }

    // ---- emission from stw[cur] (output rows active every sweep) -----------
    int cnt = 0;
    if (inimg && y >= r0 && y < r0 + 16) {
        const uint32_t w = stw[cur][sbase];
        if (FIRST) {
            ((uint32_t*)(state2 + (size_t)img * HW))[y * 32 + q] = w;
        } else {
            float* om = out + NM + (size_t)img * HW;
            *(float4*)(om + y * 128 + xc) =
                make_float4((float)(w & 1), (float)((w >> 8) & 1),
                            (float)((w >> 16) & 1), (float)((w >> 24) & 1));
            cnt = __popc(w & 0x01010101u);
        }
    }

    // ---- phase B tail: counts + valid (proven ticket) ----------------------
    if (!FIRST) {
        __syncthreads();   // before plane reuse as cred
        int* cred = (int*)plane;
        cred[tid] = cnt;
        if (tid < 192) cred[832 + tid] = 0;   // pad to 1024
        __syncthreads();
        for (int off = 512; off > 0; off >>= 1) {
            if (tid < off) cred[tid] += cred[tid + off];
            __syncthreads();
        }
        int* flag = (int*)&stw[0][0];
        if (tid == 0) {
            atomicAdd(&counters[img], cred[0]);
            __threadfence();
            int old = atomicAdd(&counters[NI], 1);
            flag[0] = (old == 511) ? 1 : 0;
        }
        __syncthreads();
        if (flag[0] && tid < NI) {
            int c = atomicAdd(&counters[tid], 0);
            // 16384*0.05 = 819.2, 16384*0.95 = 15564.8; counts are integers
            out[NM + (size_t)NI * HW + tid] = (c >= 820 && c <= 15564) ? 1.0f : 0.0f;
        }
    }
}

extern "C" void kernel_launch(void* const* d_in, const int* in_sizes, int n_in,
                              void* d_out, int out_size, void* d_ws, size_t ws_size,
                              hipStream_t stream) {
    const float* seg = (const float*)d_in[0];
    const float* cate_scores = (const float*)d_in[1];
    const float* feat = (const float*)d_in[2];
    const float* x = (const float*)d_in[3];
    const float* targets = (const float*)d_in[4];
    const int* labels = (const int*)d_in[5];
    float* out = (float*)d_out;
    char* ws = (char*)d_ws;

    unsigned char* state2 = (unsigned char*)(ws + OFF_STATE2);
    unsigned long long* packed = (unsigned long long*)(ws + OFF_PACKED);
    float* diouT = (float*)(ws + OFF_DIOUT);
    float* compm = (float*)(ws + OFF_COMPM);
    int* counters = (int*)(ws + OFF_CNT);

    // Node 1: CRF iters 1-5 + fused mask-pack + iter-0 state + counter zero
    crf5_kernel<true><<<512, 832, 0, stream>>>(feat, cate_scores, diouT, compm,
                                               seg, packed, x, targets, state2,
                                               out, counters);
    // Node 2: NMS diou + compm (needs packed from node 1)
    diou_compm_kernel<<<NM, 256, 0, stream>>>(packed, labels, diouT, compm);
    // Node 3: coef + CRF iters 6-10 + masks/counts/valid
    crf5_kernel<false><<<512, 832, 0, stream>>>(feat, cate_scores, diouT, compm,
                                                seg, packed, x, targets, state2,
                                                out, counters);
}

// Round 14
// 186.503 us; speedup vs baseline: 1.3989x; 1.0143x over previous
//
#include <hip/hip_runtime.h>
#include <stdint.h>

#define HW 16384
#define NI 64
#define NM 256
#define WORDS 256

// plane padding: stride 136 floats/row (4 guard cols each side, zeroed)
#define PR 136
#define PSZ (26 * PR)   // 3536 floats per plane
// state padding: stride 34 words/row (1 guard word each side, zeroed)
#define SR 34

// ws layout (~31 MB used)
#define OFF_STATE2 (1u << 20)    // 1 MB state bytes (iter-5 handoff A->B)
#define OFF_PACKED (2u << 20)    // 512 KB bit-packed masks [word][mask]
#define OFF_DIOUT  0x280000u     // 256 KB diou transposed diouT[col][row]
#define OFF_COMPM  0x2C0000u
#define OFF_CNT    0x2C1000u     // 64 counters + done ticket at [64]
#define OFF_GPLANE 0x300000u     // 27.3 MB plane spill A->B

// ---------------- fused diou + compm (proven) -------------------------------
__global__ __launch_bounds__(256) void diou_compm_kernel(
    const unsigned long long* __restrict__ packed, const int* __restrict__ labels,
    float* __restrict__ diouT, float* __restrict__ compm) {
    #pragma clang fp contract(off)
    __shared__ unsigned long long colj[WORDS];
    __shared__ float red[NM];
    const int j = blockIdx.x, i = threadIdx.x;
    colj[i] = packed[i * NM + j];
    __syncthreads();
    int inter = 0, si = 0, sj = 0;
    for (int w = 0; w < WORDS; ++w) {
        unsigned long long a = colj[w];
        unsigned long long b = packed[w * NM + i];
        inter += __popcll(a & b);
        sj += __popcll(a);
        si += __popcll(b);
    }
    float d = 0.0f;
    if (j > i && labels[i] == labels[j]) {
        float u = (float)(si + sj - inter);   // exact integers in f32
        d = (float)inter / u;
    }
    diouT[j * NM + i] = d;
    red[i] = d;
    __syncthreads();
    for (int off = 128; off > 0; off >>= 1) {
        if (i < off) red[i] = fmaxf(red[i], red[i + off]);
        __syncthreads();
    }
    if (i == 0) {
        float m = red[0];
        float t = m * m;
        compm[j] = expf(-2.0f * t);
    }
}

// ---------------- CRF: 5 iters/launch (R13-proven body + memoization) -------
// 512 blocks = 64 img x 8 tiles of 16 rows; 832 threads = 26-row window x 32
// quads. Planes k=0..3 in LDS (mirror identity, exact; center==3.0f; OOB
// kw==0 exactly). Zero-padded guards: branchless taps (a += lx*0 == a exact).
// Sweep s computes rows [max(0,r0-4+s), min(128,r0+20-s)) — proven bit-exact.
// NEW (value-exact memoization, no float-op change):
//  - per-thread skip: if this thread's 9 input words equal those of its last
//    computed sweep, output := cached output (deterministic map).
//  - plane spill: A dumps LDS planes to gplane; B loads instead of recompute.
template <bool FIRST>
__global__ __launch_bounds__(832, 6) void crf5_kernel(
    const float* __restrict__ feat, const float* __restrict__ scores,
    const float* __restrict__ diouT, const float* __restrict__ compm,
    const float* __restrict__ seg, unsigned long long* __restrict__ packed,
    const float* __restrict__ x, const float* __restrict__ targets,
    unsigned char* __restrict__ state2, float* __restrict__ gplane,
    float* __restrict__ out, int* __restrict__ counters) {
    #pragma clang fp contract(off)
    __shared__ float plane[4 * PSZ];      // 56576 B
    __shared__ uint32_t stw[2][26 * SR];  // 7072 B
    __shared__ int chg;                   // total 63652 B < 64 KiB
    const int tid = threadIdx.x, bid = blockIdx.x;
    const int img = bid >> 3, r0 = (bid & 7) * 16;
    const int w0 = r0 - 5;
    const int rel = tid >> 5;             // 0..25
    const int q = tid & 31;
    const int xc = q * 4;
    const int y = w0 + rel;
    const bool inimg = (unsigned)y < 128u;

    if (FIRST) {
        // ---- pack (fused; proven ballot body) -----------------------------
        const int wave = tid >> 6, lane = tid & 63;
        const int gw = bid * 13 + wave;          // 6656 waves; 4096 used
        if (gw < 4096) {
            for (int t = 0; t < 16; ++t) {
                int gwi = gw * 16 + t;           // [0, 65536)
                int i = gwi >> 8, w = gwi & 255;
                float v = seg[(size_t)i * HW + w * 64 + lane];
                unsigned long long m = __ballot(v > 0.5f);
                if (lane == 0) packed[w * NM + i] = m;
            }
        }
        if (bid == 0 && tid < NI + 1) counters[tid] = 0;  // [64] = ticket
    } else {
        // ---- coef prologue (blocks 0..255) — plane as scratch -------------
        if (bid < NM) {
            float* red = plane;
            if (tid < NM) {
                float d = diouT[bid * NM + tid];
                float dd = d * d;
                float dec = expf(-2.0f * dd);
                red[tid] = dec / compm[tid];
            }
            __syncthreads();
            for (int off = 128; off > 0; off >>= 1) {
                if (tid < off) red[tid] = fminf(red[tid], red[tid + off]);
                __syncthreads();
            }
            if (tid == 0) out[bid] = scores[bid] * red[0];
            __syncthreads();
        }
    }

    // ---- planes: A computes (proven sequence) + spills; B reloads ----------
    if (FIRST) {
        const float* fb = feat + (size_t)img * 3 * HW;
        float c0[4], c1[4], c2[4];
        if (inimg) {
            const int pp = y * 128 + xc;
            float4 cv0 = *(const float4*)&fb[pp];
            float4 cv1 = *(const float4*)&fb[HW + pp];
            float4 cv2 = *(const float4*)&fb[2 * HW + pp];
            c0[0]=cv0.x+10.0f; c0[1]=cv0.y+10.0f; c0[2]=cv0.z+10.0f; c0[3]=cv0.w+10.0f;
            c1[0]=cv1.x+10.0f; c1[1]=cv1.y+10.0f; c1[2]=cv1.z+10.0f; c1[3]=cv1.w+10.0f;
            c2[0]=cv2.x+10.0f; c2[1]=cv2.y+10.0f; c2[2]=cv2.z+10.0f; c2[3]=cv2.w+10.0f;
        }
        #pragma unroll
        for (int k = 0; k < 4; ++k) {
            const int dy = (k < 3) ? -1 : 0;
            const int dx = (k < 3) ? (k - 1) : -1;
            float res[4] = {0.0f, 0.0f, 0.0f, 0.0f};
            if (inimg) {
                const int ny = y + dy;
                if ((unsigned)ny < 128u) {
                    #pragma unroll
                    for (int j = 0; j < 4; ++j) {
                        const int nx = xc + j + dx;
                        if ((unsigned)nx < 128u) {
                            const int qq = ny * 128 + nx;
                            float u0 = fb[qq] + 10.0f;
                            float u1 = fb[HW + qq] + 10.0f;
                            float u2 = fb[2 * HW + qq] + 10.0f;
                            float d0 = u0 - c0[j], d1 = u1 - c1[j], d2 = u2 - c2[j];
                            float ss = d0 * d0;
                            ss = ss + d1 * d1;
                            ss = ss + d2 * d2;
                            float color = (-ss) / 0.5f;
                            float sp = (float)(dy * dy + dx * dx) / 1800.0f;
                            res[j] = 3.0f * expf(color - sp);
                        }
                    }
                }
            }
            float4 r4 = make_float4(res[0], res[1], res[2], res[3]);
            *(float4*)&plane[k * PSZ + rel * PR + 4 + xc] = r4;
            *(float4*)&gplane[(((size_t)bid * 4 + k) * 26 + rel) * 128 + xc] = r4;
            if (q == 0)
                *(float4*)&plane[k * PSZ + rel * PR + 0] = make_float4(0, 0, 0, 0);
            if (q == 31)
                *(float4*)&plane[k * PSZ + rel * PR + 132] = make_float4(0, 0, 0, 0);
        }
    } else {
        #pragma unroll
        for (int k = 0; k < 4; ++k) {
            float4 v = *(const float4*)&gplane[(((size_t)bid * 4 + k) * 26 + rel) * 128 + xc];
            *(float4*)&plane[k * PSZ + rel * PR + 4 + xc] = v;
            if (q == 0)
                *(float4*)&plane[k * PSZ + rel * PR + 0] = make_float4(0, 0, 0, 0);
            if (q == 31)
                *(float4*)&plane[k * PSZ + rel * PR + 132] = make_float4(0, 0, 0, 0);
        }
    }
    // ---- state staging (proven) --------------------------------------------
    {
        uint32_t st = 0;
        if (inimg) {
            if (FIRST) {
                const size_t gp = (size_t)img * HW + y * 128 + xc;
                const float4 xv = *(const float4*)(x + gp);
                const float4 tv = *(const float4*)(targets + gp);
                float xs[4] = {xv.x, xv.y, xv.z, xv.w};
                float ts[4] = {tv.x, tv.y, tv.z, tv.w};
                #pragma unroll
                for (int j = 0; j < 4; ++j) {
                    float xt = xs[j] * ts[j];
                    int b1 = (xt > 0.5f) ? 1 : 0;
                    int tb = (ts[j] > 0.5f) ? 1 : 0;
                    st |= (uint32_t)(b1 | ((b1 ^ 1) << 1) | (tb << 2)) << (8 * j);
                }
            } else {
                st = ((const uint32_t*)(state2 + (size_t)img * HW + y * 128))[q];
            }
        }
        stw[0][rel * SR + 1 + q] = st;
        if (!inimg) stw[1][rel * SR + 1 + q] = 0;
        if (q == 0)  { stw[0][rel * SR + 0]  = 0; stw[1][rel * SR + 0]  = 0; }
        if (q == 31) { stw[0][rel * SR + 33] = 0; stw[1][rel * SR + 33] = 0; }
    }
    __syncthreads();

    // ---- 5 sweeps: branchless taps + per-thread memo + block early-exit ----
    const float l45 = 0.7985076962177716f;  // -log(0.45f)
    const float l55 = 0.5978370007556204f;  // -log(0.55f)
    const bool compute = inimg && (y >= r0 - 4) && (y < r0 + 20);
    const int lane = tid & 63;
    const int rbase = rel * PR + 4 + xc;
    const int sbase = rel * SR + 1 + q;
    uint32_t pin[9];
    uint32_t powv = 0;
    bool haveprev = false;
    int cur = 0;
    for (int s = 0; s < 5; ++s) {
        if (tid == 0) chg = 0;
        __syncthreads();
        const int lo = (r0 - 4 + s < 0) ? 0 : r0 - 4 + s;
        const int hi = (r0 + 20 - s > 128) ? 128 : r0 + 20 - s;
        const bool act = compute && (y >= lo) && (y < hi);
        bool changed = false;
        if (act) {
            const uint32_t* sw = &stw[cur][0];
            uint32_t in9[9];
            #pragma unroll
            for (int r = 0; r < 3; ++r) {
                const int base = sbase + (r - 1) * SR;
                in9[r * 3 + 0] = sw[base - 1];
                in9[r * 3 + 1] = sw[base];
                in9[r * 3 + 2] = sw[base + 1];
            }
            const uint32_t wcen = in9[4];
            bool same = haveprev;
            #pragma unroll
            for (int m = 0; m < 9; ++m) same = same && (in9[m] == pin[m]);
            uint32_t ow;
            if (same) {
                ow = powv;  // deterministic map on identical inputs — exact
            } else {
                float lx1r[3][6], lx0r[3][6];
                #pragma unroll
                for (int r = 0; r < 3; ++r) {
                    const uint32_t wm = in9[r * 3 + 0];
                    const uint32_t wc = in9[r * 3 + 1];
                    const uint32_t wp = in9[r * 3 + 2];
                    unsigned char b[6];
                    b[0] = wm >> 24;
                    b[1] = wc & 0xff; b[2] = (wc >> 8) & 0xff;
                    b[3] = (wc >> 16) & 0xff; b[4] = wc >> 24;
                    b[5] = wp & 0xff;
                    #pragma unroll
                    for (int m = 0; m < 6; ++m) {
                        lx1r[r][m] = (b[m] & 1) ? l55 : l45;
                        lx0r[r][m] = (b[m] & 2) ? l55 : l45;
                    }
                }
                // kw gather: 7 x b128 + 3 scalars via mirror identity
                float4 p0a = *(const float4*)&plane[0 * PSZ + rbase];
                float4 p1a = *(const float4*)&plane[1 * PSZ + rbase];
                float4 p2a = *(const float4*)&plane[2 * PSZ + rbase];
                float4 p3a = *(const float4*)&plane[3 * PSZ + rbase];
                float4 p0b = *(const float4*)&plane[0 * PSZ + rbase + PR];
                float4 p1b = *(const float4*)&plane[1 * PSZ + rbase + PR];
                float4 p2b = *(const float4*)&plane[2 * PSZ + rbase + PR];
                float s5 = plane[3 * PSZ + rbase + 4];
                float s6 = plane[2 * PSZ + rbase + PR - 1];
                float s8 = plane[0 * PSZ + rbase + PR + 4];
                const float kw[9][4] = {
                    {p0a.x, p0a.y, p0a.z, p0a.w},
                    {p1a.x, p1a.y, p1a.z, p1a.w},
                    {p2a.x, p2a.y, p2a.z, p2a.w},
                    {p3a.x, p3a.y, p3a.z, p3a.w},
                    {3.0f, 3.0f, 3.0f, 3.0f},
                    {p3a.y, p3a.z, p3a.w, s5},
                    {s6, p2b.x, p2b.y, p2b.z},
                    {p1b.x, p1b.y, p1b.z, p1b.w},
                    {p0b.y, p0b.z, p0b.w, s8}};
                float a0[4] = {0.f, 0.f, 0.f, 0.f}, a1[4] = {0.f, 0.f, 0.f, 0.f};
                #pragma unroll
                for (int k = 0; k < 9; ++k) {
                    const int r = k / 3, m0 = k % 3;
                    #pragma unroll
                    for (int j = 0; j < 4; ++j) {
                        const float kwv = kw[k][j];
                        const float t1 = lx1r[r][j + m0] * kwv;  // mul then add
                        const float t0 = lx0r[r][j + m0] * kwv;
                        a1[j] = a1[j] + t1;
                        a0[j] = a0[j] + t0;
                    }
                }
                // epilogue (proven exact sequence)
                ow = 0;
                #pragma unroll
                for (int j = 0; j < 4; ++j) {
                    const unsigned char sc = (wcen >> (8 * j)) & 0xffu;
                    const float tval = (sc & 4) ? 1.0f : 0.0f;
                    const float e1 = expf(-a1[j]);
                    const float e0 = expf(-a0[j]);
                    const float m1 = e1 * tval;
                    const float f1 = m1 + 1e-6f;
                    const float f0 = e0 + 1e-6f;
                    const float den = f0 + f1;
                    const float r1 = f1 / den;
                    const float r0v = f0 / den;
                    const int s1 = (r1 > 0.5f) ? 1 : 0;
                    const int s0 = (r0v > 0.5f) ? 1 : 0;
                    ow |= (uint32_t)(s1 | (s0 << 1) | (sc & 4)) << (8 * j);
                }
                #pragma unroll
                for (int m = 0; m < 9; ++m) pin[m] = in9[m];
                powv = ow;
                haveprev = true;
            }
            stw[cur ^ 1][sbase] = ow;
            changed = (ow != wcen);
        }
        unsigned long long bal = __ballot(changed);
        if (lane == 0 && bal) atomicOr(&chg, 1);
        __syncthreads();
        if (chg == 0) break;   // fixed point: all later sweeps identical (exact)
        cur ^= 1;
    }

    // ---- emission from stw[cur] --------------------------------------------
    int cnt = 0;
    if (inimg && y >= r0 && y < r0 + 16) {
        const uint32_t w = stw[cur][sbase];
        if (FIRST) {
            ((uint32_t*)(state2 + (size_t)img * HW))[y * 32 + q] = w;
        } else {
            float* om = out + NM + (size_t)img * HW;
            *(float4*)(om + y * 128 + xc) =
                make_float4((float)(w & 1), (float)((w >> 8) & 1),
                            (float)((w >> 16) & 1), (float)((w >> 24) & 1));
            cnt = __popc(w & 0x01010101u);
        }
    }

    // ---- phase B tail: counts + valid (proven ticket) ----------------------
    if (!FIRST) {
        __syncthreads();   // before plane reuse as cred
        int* cred = (int*)plane;
        cred[tid] = cnt;
        if (tid < 192) cred[832 + tid] = 0;   // pad to 1024
        __syncthreads();
        for (int off = 512; off > 0; off >>= 1) {
            if (tid < off) cred[tid] += cred[tid + off];
            __syncthreads();
        }
        int* flag = (int*)&stw[0][0];
        if (tid == 0) {
            atomicAdd(&counters[img], cred[0]);
            __threadfence();
            int old = atomicAdd(&counters[NI], 1);
            flag[0] = (old == 511) ? 1 : 0;
        }
        __syncthreads();
        if (flag[0] && tid < NI) {
            int c = atomicAdd(&counters[tid], 0);
            // 16384*0.05 = 819.2, 16384*0.95 = 15564.8; counts are integers
            out[NM + (size_t)NI * HW + tid] = (c >= 820 && c <= 15564) ? 1.0f : 0.0f;
        }
    }
}

extern "C" void kernel_launch(void* const* d_in, const int* in_sizes, int n_in,
                              void* d_out, int out_size, void* d_ws, size_t ws_size,
                              hipStream_t stream) {
    const float* seg = (const float*)d_in[0];
    const float* cate_scores = (const float*)d_in[1];
    const float* feat = (const float*)d_in[2];
    const float* x = (const float*)d_in[3];
    const float* targets = (const float*)d_in[4];
    const int* labels = (const int*)d_in[5];
    float* out = (float*)d_out;
    char* ws = (char*)d_ws;

    unsigned char* state2 = (unsigned char*)(ws + OFF_STATE2);
    unsigned long long* packed = (unsigned long long*)(ws + OFF_PACKED);
    float* diouT = (float*)(ws + OFF_DIOUT);
    float* compm = (float*)(ws + OFF_COMPM);
    int* counters = (int*)(ws + OFF_CNT);
    float* gplane = (float*)(ws + OFF_GPLANE);

    // Node 1: CRF iters 1-5 + mask-pack + iter-0 state + plane spill
    crf5_kernel<true><<<512, 832, 0, stream>>>(feat, cate_scores, diouT, compm,
                                               seg, packed, x, targets, state2,
                                               gplane, out, counters);
    // Node 2: NMS diou + compm (needs packed from node 1)
    diou_compm_kernel<<<NM, 256, 0, stream>>>(packed, labels, diouT, compm);
    // Node 3: coef + CRF iters 6-10 (planes from gplane) + masks/counts/valid
    crf5_kernel<false><<<512, 832, 0, stream>>>(feat, cate_scores, diouT, compm,
                                                seg, packed, x, targets, state2,
                                                gplane, out, counters);
}